// Round 1
// baseline (391.506 us; speedup 1.0000x reference)
//
#include <hip/hip_runtime.h>

#define N_VOX 100000
#define K3 125
#define IMG_C 64
#define PTS_C 32
#define OUT_C 16
#define EPSF 1e-5f

// ws layout (floats):
//   [0,      128000)  W_img_t [125][16][64]   (transposed [k][o][c])
//   [128000, 192000)  W_pts_t [125][16][32]
//   [192000, 256000)  W_vis1_t[125][16][32]
//   [256000, 3456000) cat [N][32]  (img|pts after bn+relu)
#define WIT 0
#define WPT 128000
#define WVT 192000
#define CATOFF 256000

__global__ __launch_bounds__(256) void prep_transpose(
    const float* __restrict__ Wi, const float* __restrict__ Wp,
    const float* __restrict__ Wv, float* __restrict__ ws)
{
    int i = blockIdx.x * 256 + threadIdx.x;
    if (i < 125 * 64 * 16) {
        int k = i >> 10, r = i & 1023;
        int c = r >> 4, o = r & 15;
        ws[WIT + k * 1024 + o * 64 + c] = Wi[i];
    }
    if (i < 125 * 32 * 16) {
        int k = i / 512, r = i % 512;
        int c = r >> 4, o = r & 15;
        ws[WPT + k * 512 + o * 32 + c] = Wp[i];
        ws[WVT + k * 512 + o * 32 + c] = Wv[i];
    }
}

// Kernel A: fused img-conv + pts-conv + BN + ReLU -> cat[N][32]
// One wave per voxel. Lane = cs*16 + o  (cs = c-slice 0..3, o = out channel).
__global__ __launch_bounds__(256) void convA(
    const float* __restrict__ fimg, const float* __restrict__ fpts,
    const int* __restrict__ nbr, float* __restrict__ ws,
    const float* __restrict__ gi, const float* __restrict__ bi,
    const float* __restrict__ mi, const float* __restrict__ vi,
    const float* __restrict__ gp, const float* __restrict__ bp,
    const float* __restrict__ mp, const float* __restrict__ vp)
{
    int wid = threadIdx.x >> 6;
    int lane = threadIdx.x & 63;
    int n = blockIdx.x * 4 + wid;
    if (n >= N_VOX) return;
    int o = lane & 15, cs = lane >> 4;

    __shared__ float lds[4][96];
    float* fs = lds[wid];

    const float* __restrict__ Wi = ws + WIT;
    const float* __restrict__ Wp = ws + WPT;
    float* __restrict__ cat = ws + CATOFF;

    float accI = 0.f, accP = 0.f;

    const int* row = nbr + (long)n * K3;
    #pragma unroll
    for (int h = 0; h < 2; ++h) {
        int kl = h * 64 + lane;
        int idx = (kl < K3) ? row[kl] : N_VOX;
        unsigned long long mask = __ballot(idx < N_VOX);
        while (mask) {
            int b = __builtin_ctzll(mask);
            mask &= mask - 1;
            int j = __shfl(idx, b);
            int k = h * 64 + b;
            // stage gathered feature rows into this wave's LDS slot
            fs[lane] = fimg[(long)j * IMG_C + lane];
            if (lane < 32) fs[64 + lane] = fpts[(long)j * PTS_C + lane];
            // img: lane sums c in [cs*16, cs*16+16)
            const float4* wi4 = (const float4*)(Wi + k * 1024 + o * 64 + cs * 16);
            const float4* f4  = (const float4*)(fs + cs * 16);
            #pragma unroll
            for (int t = 0; t < 4; ++t) {
                float4 w = wi4[t], f = f4[t];
                accI += w.x * f.x + w.y * f.y + w.z * f.z + w.w * f.w;
            }
            // pts: lane sums c in [cs*8, cs*8+8)
            const float4* wp4 = (const float4*)(Wp + k * 512 + o * 32 + cs * 8);
            const float4* fp4 = (const float4*)(fs + 64 + cs * 8);
            #pragma unroll
            for (int t = 0; t < 2; ++t) {
                float4 w = wp4[t], f = fp4[t];
                accP += w.x * f.x + w.y * f.y + w.z * f.z + w.w * f.w;
            }
        }
    }
    // reduce partial sums across the 4 c-slices (lanes o, o+16, o+32, o+48)
    accI += __shfl_xor(accI, 16); accI += __shfl_xor(accI, 32);
    accP += __shfl_xor(accP, 16); accP += __shfl_xor(accP, 32);

    if (lane < 16) {
        float si = gi[o] * rsqrtf(vi[o] + EPSF);
        float xi = fmaxf((accI - mi[o]) * si + bi[o], 0.f);
        float sp = gp[o] * rsqrtf(vp[o] + EPSF);
        float xp = fmaxf((accP - mp[o]) * sp + bp[o], 0.f);
        cat[(long)n * 32 + o] = xi;
        cat[(long)n * 32 + 16 + o] = xp;
    }
}

// Kernel B: vis-conv on cat + BN + ReLU + sigmoid gate + blend -> out[N][16]
__global__ __launch_bounds__(256) void convB(
    const int* __restrict__ nbr, const float* __restrict__ ws,
    const float* __restrict__ gv, const float* __restrict__ bv,
    const float* __restrict__ mv, const float* __restrict__ vv,
    const float* __restrict__ w2, float* __restrict__ out)
{
    int wid = threadIdx.x >> 6;
    int lane = threadIdx.x & 63;
    int n = blockIdx.x * 4 + wid;
    if (n >= N_VOX) return;
    int o = lane & 15, cs = lane >> 4;

    __shared__ float lds[4][32];
    float* fs = lds[wid];

    const float* __restrict__ Wv = ws + WVT;
    const float* __restrict__ cat = ws + CATOFF;

    float acc = 0.f;
    const int* row = nbr + (long)n * K3;
    #pragma unroll
    for (int h = 0; h < 2; ++h) {
        int kl = h * 64 + lane;
        int idx = (kl < K3) ? row[kl] : N_VOX;
        unsigned long long mask = __ballot(idx < N_VOX);
        while (mask) {
            int b = __builtin_ctzll(mask);
            mask &= mask - 1;
            int j = __shfl(idx, b);
            int k = h * 64 + b;
            if (lane < 32) fs[lane] = cat[(long)j * 32 + lane];
            const float4* wv4 = (const float4*)(Wv + k * 512 + o * 32 + cs * 8);
            const float4* f4  = (const float4*)(fs + cs * 8);
            #pragma unroll
            for (int t = 0; t < 2; ++t) {
                float4 w = wv4[t], f = f4[t];
                acc += w.x * f.x + w.y * f.y + w.z * f.z + w.w * f.w;
            }
        }
    }
    acc += __shfl_xor(acc, 16); acc += __shfl_xor(acc, 32);

    // bn+relu (all lanes have the o = lane%16 sum)
    float s = gv[o] * rsqrtf(vv[o] + EPSF);
    float hh = fmaxf((acc - mv[o]) * s + bv[o], 0.f);
    // dot with W_vis2 over the 16 output channels
    float p = hh * w2[o];
    p += __shfl_xor(p, 1); p += __shfl_xor(p, 2);
    p += __shfl_xor(p, 4); p += __shfl_xor(p, 8);
    float vis = 1.f / (1.f + __expf(-p));

    if (lane < 16) {
        float xi = cat[(long)n * 32 + o];
        float xp = cat[(long)n * 32 + 16 + o];
        out[(long)n * 16 + o] = vis * xi + (1.f - vis) * xp;
    }
}

extern "C" void kernel_launch(void* const* d_in, const int* in_sizes, int n_in,
                              void* d_out, int out_size, void* d_ws, size_t ws_size,
                              hipStream_t stream) {
    const float* fimg = (const float*)d_in[0];
    const float* fpts = (const float*)d_in[1];
    const int*   nbr  = (const int*)d_in[2];
    const float* Wimg = (const float*)d_in[3];
    const float* gi = (const float*)d_in[4];
    const float* bi = (const float*)d_in[5];
    const float* mi = (const float*)d_in[6];
    const float* vi = (const float*)d_in[7];
    const float* Wpts = (const float*)d_in[8];
    const float* gp = (const float*)d_in[9];
    const float* bp = (const float*)d_in[10];
    const float* mp = (const float*)d_in[11];
    const float* vp = (const float*)d_in[12];
    const float* Wvis = (const float*)d_in[13];
    const float* gv = (const float*)d_in[14];
    const float* bv = (const float*)d_in[15];
    const float* mv = (const float*)d_in[16];
    const float* vv = (const float*)d_in[17];
    const float* w2 = (const float*)d_in[18];
    float* out = (float*)d_out;
    float* ws = (float*)d_ws;

    hipLaunchKernelGGL(prep_transpose, dim3(500), dim3(256), 0, stream,
                       Wimg, Wpts, Wvis, ws);
    hipLaunchKernelGGL(convA, dim3(N_VOX / 4), dim3(256), 0, stream,
                       fimg, fpts, nbr, ws, gi, bi, mi, vi, gp, bp, mp, vp);
    hipLaunchKernelGGL(convB, dim3(N_VOX / 4), dim3(256), 0, stream,
                       nbr, ws, gv, bv, mv, vv, w2, out);
}

// Round 2
// 202.474 us; speedup vs baseline: 1.9336x; 1.9336x over previous
//
#include <hip/hip_runtime.h>

#define N_VOX 100000
#define K3 125
#define IMG_C 64
#define PTS_C 32
#define OUT_C 16
#define EPSF 1e-5f

// ws layout (floats):
//   [0,      128000)  W_img_l [125][4][64][4]  (lane-order: [k][t][lane][e], lane=cs*16+o, c=cs*16+t*4+e)
//   [128000, 192000)  W_pts_l [125][2][64][4]  (lane=cs*16+o, c=cs*8+t*4+e)
//   [192000, 256000)  W_vis_l [125][2][64][4]
//   [256000, 3456000) cat [N][32]  (img|pts after bn+relu)
#define WIT 0
#define WPT 128000
#define WVT 192000
#define CATOFF 256000

__global__ __launch_bounds__(256) void prep_transpose(
    const float* __restrict__ Wi, const float* __restrict__ Wp,
    const float* __restrict__ Wv, float* __restrict__ ws)
{
    int i = blockIdx.x * 256 + threadIdx.x;
    if (i < 125 * 64 * 16) {
        // Wi layout [k][c][o]: i = k*1024 + c*16 + o
        int k = i >> 10, r = i & 1023;
        int c = r >> 4, o = r & 15;
        int cs = c >> 4, t = (c >> 2) & 3, e = c & 3;
        ws[WIT + k * 1024 + t * 256 + (cs * 16 + o) * 4 + e] = Wi[i];
    }
    if (i < 125 * 32 * 16) {
        int k = i / 512, r = i % 512;
        int c = r >> 4, o = r & 15;
        int cs = c >> 3, t = (c >> 2) & 1, e = c & 3;
        ws[WPT + k * 512 + t * 256 + (cs * 16 + o) * 4 + e] = Wp[i];
        ws[WVT + k * 512 + t * 256 + (cs * 16 + o) * 4 + e] = Wv[i];
    }
}

// Kernel A: fused img-conv + pts-conv + BN + ReLU -> cat[N][32]
// One wave per voxel. Lane = cs*16 + o  (cs = c-slice 0..3, o = out channel).
__global__ __launch_bounds__(256) void convA(
    const float* __restrict__ fimg, const float* __restrict__ fpts,
    const int* __restrict__ nbr, float* __restrict__ ws,
    const float* __restrict__ gi, const float* __restrict__ bi,
    const float* __restrict__ mi, const float* __restrict__ vi,
    const float* __restrict__ gp, const float* __restrict__ bp,
    const float* __restrict__ mp, const float* __restrict__ vp)
{
    int wid = threadIdx.x >> 6;
    int lane = threadIdx.x & 63;
    int n = blockIdx.x * 4 + wid;
    if (n >= N_VOX) return;
    int o = lane & 15, cs = lane >> 4;

    __shared__ float lds[4][96];
    float* fs = lds[wid];

    const float* __restrict__ Wi = ws + WIT;
    const float* __restrict__ Wp = ws + WPT;
    float* __restrict__ cat = ws + CATOFF;

    float accI = 0.f, accP = 0.f;

    const int* row = nbr + (long)n * K3;
    #pragma unroll
    for (int h = 0; h < 2; ++h) {
        int kl = h * 64 + lane;
        int idx = (kl < K3) ? row[kl] : N_VOX;
        unsigned long long mask = __ballot(idx < N_VOX);
        while (mask) {
            int b = __builtin_ctzll(mask);
            mask &= mask - 1;
            int j = __shfl(idx, b);
            int k = h * 64 + b;
            // stage gathered feature rows into this wave's LDS slot
            fs[lane] = fimg[(long)j * IMG_C + lane];
            if (lane < 32) fs[64 + lane] = fpts[(long)j * PTS_C + lane];
            // img: lane sums c in [cs*16, cs*16+16) — W loads are contiguous 1KB/instr
            const float4* wi4 = (const float4*)(Wi + k * 1024);
            const float4* f4  = (const float4*)(fs + cs * 16);
            #pragma unroll
            for (int t = 0; t < 4; ++t) {
                float4 w = wi4[t * 64 + lane], f = f4[t];
                accI += w.x * f.x + w.y * f.y + w.z * f.z + w.w * f.w;
            }
            // pts: lane sums c in [cs*8, cs*8+8)
            const float4* wp4 = (const float4*)(Wp + k * 512);
            const float4* fp4 = (const float4*)(fs + 64 + cs * 8);
            #pragma unroll
            for (int t = 0; t < 2; ++t) {
                float4 w = wp4[t * 64 + lane], f = fp4[t];
                accP += w.x * f.x + w.y * f.y + w.z * f.z + w.w * f.w;
            }
        }
    }
    // reduce partial sums across the 4 c-slices (lanes o, o+16, o+32, o+48)
    accI += __shfl_xor(accI, 16); accI += __shfl_xor(accI, 32);
    accP += __shfl_xor(accP, 16); accP += __shfl_xor(accP, 32);

    if (lane < 16) {
        float si = gi[o] * rsqrtf(vi[o] + EPSF);
        float xi = fmaxf((accI - mi[o]) * si + bi[o], 0.f);
        float sp = gp[o] * rsqrtf(vp[o] + EPSF);
        float xp = fmaxf((accP - mp[o]) * sp + bp[o], 0.f);
        cat[(long)n * 32 + o] = xi;
        cat[(long)n * 32 + 16 + o] = xp;
    }
}

// Kernel B: vis-conv on cat + BN + ReLU + sigmoid gate + blend -> out[N][16]
__global__ __launch_bounds__(256) void convB(
    const int* __restrict__ nbr, const float* __restrict__ ws,
    const float* __restrict__ gv, const float* __restrict__ bv,
    const float* __restrict__ mv, const float* __restrict__ vv,
    const float* __restrict__ w2, float* __restrict__ out)
{
    int wid = threadIdx.x >> 6;
    int lane = threadIdx.x & 63;
    int n = blockIdx.x * 4 + wid;
    if (n >= N_VOX) return;
    int o = lane & 15, cs = lane >> 4;

    __shared__ float lds[4][32];
    float* fs = lds[wid];

    const float* __restrict__ Wv = ws + WVT;
    const float* __restrict__ cat = ws + CATOFF;

    float acc = 0.f;
    const int* row = nbr + (long)n * K3;
    #pragma unroll
    for (int h = 0; h < 2; ++h) {
        int kl = h * 64 + lane;
        int idx = (kl < K3) ? row[kl] : N_VOX;
        unsigned long long mask = __ballot(idx < N_VOX);
        while (mask) {
            int b = __builtin_ctzll(mask);
            mask &= mask - 1;
            int j = __shfl(idx, b);
            int k = h * 64 + b;
            if (lane < 32) fs[lane] = cat[(long)j * 32 + lane];
            const float4* wv4 = (const float4*)(Wv + k * 512);
            const float4* f4  = (const float4*)(fs + cs * 8);
            #pragma unroll
            for (int t = 0; t < 2; ++t) {
                float4 w = wv4[t * 64 + lane], f = f4[t];
                acc += w.x * f.x + w.y * f.y + w.z * f.z + w.w * f.w;
            }
        }
    }
    acc += __shfl_xor(acc, 16); acc += __shfl_xor(acc, 32);

    // bn+relu (all lanes have the o = lane%16 sum)
    float s = gv[o] * rsqrtf(vv[o] + EPSF);
    float hh = fmaxf((acc - mv[o]) * s + bv[o], 0.f);
    // dot with W_vis2 over the 16 output channels
    float p = hh * w2[o];
    p += __shfl_xor(p, 1); p += __shfl_xor(p, 2);
    p += __shfl_xor(p, 4); p += __shfl_xor(p, 8);
    float vis = 1.f / (1.f + __expf(-p));

    if (lane < 16) {
        float xi = cat[(long)n * 32 + o];
        float xp = cat[(long)n * 32 + 16 + o];
        out[(long)n * 16 + o] = vis * xi + (1.f - vis) * xp;
    }
}

extern "C" void kernel_launch(void* const* d_in, const int* in_sizes, int n_in,
                              void* d_out, int out_size, void* d_ws, size_t ws_size,
                              hipStream_t stream) {
    const float* fimg = (const float*)d_in[0];
    const float* fpts = (const float*)d_in[1];
    const int*   nbr  = (const int*)d_in[2];
    const float* Wimg = (const float*)d_in[3];
    const float* gi = (const float*)d_in[4];
    const float* bi = (const float*)d_in[5];
    const float* mi = (const float*)d_in[6];
    const float* vi = (const float*)d_in[7];
    const float* Wpts = (const float*)d_in[8];
    const float* gp = (const float*)d_in[9];
    const float* bp = (const float*)d_in[10];
    const float* mp = (const float*)d_in[11];
    const float* vp = (const float*)d_in[12];
    const float* Wvis = (const float*)d_in[13];
    const float* gv = (const float*)d_in[14];
    const float* bv = (const float*)d_in[15];
    const float* mv = (const float*)d_in[16];
    const float* vv = (const float*)d_in[17];
    const float* w2 = (const float*)d_in[18];
    float* out = (float*)d_out;
    float* ws = (float*)d_ws;

    hipLaunchKernelGGL(prep_transpose, dim3(500), dim3(256), 0, stream,
                       Wimg, Wpts, Wvis, ws);
    hipLaunchKernelGGL(convA, dim3(N_VOX / 4), dim3(256), 0, stream,
                       fimg, fpts, nbr, ws, gi, bi, mi, vi, gp, bp, mp, vp);
    hipLaunchKernelGGL(convB, dim3(N_VOX / 4), dim3(256), 0, stream,
                       nbr, ws, gv, bv, mv, vv, w2, out);
}